// Round 1
// baseline (851.318 us; speedup 1.0000x reference)
//
#include <hip/hip_runtime.h>
#include <stdint.h>

typedef unsigned short ushort_t;
typedef short s16x8 __attribute__((ext_vector_type(8)));
typedef float f32x4 __attribute__((ext_vector_type(4)));

#define S_LEN 4096
#define D_DIM 1024
#define H_DIM 2816
#define E_NUM 8
#define ROWS_CAP 9216  // 8192 real rows + up to 8*127 pad, rounded

// ---- workspace layout (bytes) ----
#define OFF_CTL      0         // counts[8] @0, cursor[8] @64, baseP[8] @128, countP[8] @192
#define OFF_ROWTOK   1024      // int[ROWS_CAP]
#define OFF_ROWGATE  40960     // float[ROWS_CAP]
#define OFF_TOKE     81920     // int[S*2]
#define OFF_TOKG     114688    // float[S*2]
#define OFF_XG       262144                                  // bf16 [ROWS_CAP][D]
#define OFF_HBUF     (OFF_XG + (size_t)ROWS_CAP*D_DIM*2)     // bf16 [ROWS_CAP][H]
#define OFF_W1BT     (OFF_HBUF + (size_t)ROWS_CAP*H_DIM*2)   // bf16 [E][H][D]  (w1 transposed)
#define OFF_W2BT     (OFF_W1BT + (size_t)E_NUM*D_DIM*H_DIM*2)// bf16 [E][D][H]  (w2 transposed)

__device__ __forceinline__ ushort_t f2bf(float f) {
  unsigned int u = __float_as_uint(f);
  unsigned int r = (u + 0x7fffu + ((u >> 16) & 1u)) >> 16;
  return (ushort_t)r;
}

__device__ __forceinline__ void g2l16(const void* g, void* l) {
  __builtin_amdgcn_global_load_lds((const __attribute__((address_space(1))) void*)g,
                                   (__attribute__((address_space(3))) void*)l, 16, 0, 0);
}

// ---------- gating: logits -> top2 -> softmax -> counts ----------
__global__ void gate_kernel(const float* __restrict__ x, const float* __restrict__ wg,
                            const float* __restrict__ bg, int* __restrict__ tok_e,
                            float* __restrict__ tok_g, int* __restrict__ ctl) {
  int wave = threadIdx.x >> 6;
  int lane = threadIdx.x & 63;
  int s = blockIdx.x * 4 + wave;
  float acc[8];
#pragma unroll
  for (int e = 0; e < 8; e++) acc[e] = 0.f;
  const float* xr = x + (size_t)s * D_DIM;
  for (int d = lane; d < D_DIM; d += 64) {
    float xv = xr[d];
    const float4* w = (const float4*)(wg + (size_t)d * 8);
    float4 w0 = w[0], w1 = w[1];
    acc[0] += xv * w0.x; acc[1] += xv * w0.y; acc[2] += xv * w0.z; acc[3] += xv * w0.w;
    acc[4] += xv * w1.x; acc[5] += xv * w1.y; acc[6] += xv * w1.z; acc[7] += xv * w1.w;
  }
#pragma unroll
  for (int e = 0; e < 8; e++) {
    for (int off = 32; off > 0; off >>= 1) acc[e] += __shfl_xor(acc[e], off, 64);
  }
  if (lane == 0) {
    float l[8];
#pragma unroll
    for (int e = 0; e < 8; e++) l[e] = acc[e] + bg[e];
    int e0 = 0;
#pragma unroll
    for (int e = 1; e < 8; e++) if (l[e] > l[e0]) e0 = e;
    int e1 = (e0 == 0) ? 1 : 0;
#pragma unroll
    for (int e = 0; e < 8; e++) if (e != e0 && l[e] > l[e1]) e1 = e;
    float t = __expf(l[e1] - l[e0]);   // <= 1
    float p1 = t / (1.f + t);
    float p0 = 1.f - p1;
    tok_e[s * 2] = e0; tok_e[s * 2 + 1] = e1;
    tok_g[s * 2] = p0; tok_g[s * 2 + 1] = p1;
    atomicAdd(&ctl[e0], 1);
    atomicAdd(&ctl[e1], 1);
  }
}

// ---------- prefix scan over 8 experts, 128-padded ----------
__global__ void scan_kernel(int* ctl) {
  if (threadIdx.x == 0 && blockIdx.x == 0) {
    int run = 0;
    for (int e = 0; e < 8; e++) {
      int cp = (ctl[e] + 127) & ~127;
      ctl[32 + e] = run;   // baseP
      ctl[48 + e] = cp;    // countP
      run += cp;
    }
  }
}

// ---------- slot assignment ----------
__global__ void assign_kernel(const int* __restrict__ tok_e, const float* __restrict__ tok_g,
                              int* ctl, int* __restrict__ row_token, float* __restrict__ row_gate) {
  int i = blockIdx.x * blockDim.x + threadIdx.x;  // 0..8191  (= s*2+k)
  int e = tok_e[i];
  int slot = atomicAdd(&ctl[16 + e], 1);          // cursor
  int row = ctl[32 + e] + slot;                   // baseP
  row_token[row] = i >> 1;
  row_gate[row] = tok_g[i];
}

// ---------- gather x rows into expert-sorted bf16 ----------
__global__ void gather_kernel(const float* __restrict__ x, const int* __restrict__ row_token,
                              ushort_t* __restrict__ xg) {
  int row = blockIdx.x;
  int t = row_token[row];                          // pad rows: 0 (harmless, gate=0)
  float4 v = ((const float4*)(x + (size_t)t * D_DIM))[threadIdx.x];
  uint2 o;
  o.x = (unsigned)f2bf(v.x) | ((unsigned)f2bf(v.y) << 16);
  o.y = (unsigned)f2bf(v.z) | ((unsigned)f2bf(v.w) << 16);
  *(uint2*)(xg + (size_t)row * D_DIM + threadIdx.x * 4) = o;
}

// ---------- fp32 [E][R][C] -> bf16 [E][C][R] transpose+convert ----------
__global__ void convT_kernel(const float* __restrict__ in, ushort_t* __restrict__ out,
                             int R, int C) {
  __shared__ float t[32][33];
  size_t base = (size_t)blockIdx.z * R * C;
  int c = blockIdx.x * 32 + threadIdx.x;
#pragma unroll
  for (int i = 0; i < 32; i += 8) {
    int r = blockIdx.y * 32 + threadIdx.y + i;
    t[threadIdx.y + i][threadIdx.x] = in[base + (size_t)r * C + c];
  }
  __syncthreads();
  int rr = blockIdx.y * 32 + threadIdx.x;
#pragma unroll
  for (int i = 0; i < 32; i += 8) {
    int cc = blockIdx.x * 32 + threadIdx.y + i;
    out[base + (size_t)cc * R + rr] = f2bf(t[threadIdx.x][threadIdx.y + i]);
  }
}

// ---------- out init: gate-weighted b2 (also overwrites 0xAA poison) ----------
__global__ void init_out_kernel(const float* __restrict__ b2, const int* __restrict__ tok_e,
                                const float* __restrict__ tok_g, float* __restrict__ out) {
  int s = blockIdx.x;
  int e0 = tok_e[s * 2], e1 = tok_e[s * 2 + 1];
  float g0 = tok_g[s * 2], g1 = tok_g[s * 2 + 1];
  int d = threadIdx.x * 4;
  float4 a = *(const float4*)(b2 + (size_t)e0 * D_DIM + d);
  float4 b = *(const float4*)(b2 + (size_t)e1 * D_DIM + d);
  float4 o;
  o.x = g0 * a.x + g1 * b.x; o.y = g0 * a.y + g1 * b.y;
  o.z = g0 * a.z + g1 * b.z; o.w = g0 * a.w + g1 * b.w;
  *(float4*)(out + (size_t)s * D_DIM + d) = o;
}

// ---------- GEMM1: h = silu(xg @ w1^T-tile + b1), bf16 out ----------
__global__ __launch_bounds__(256) void gemm1_kernel(
    const ushort_t* __restrict__ xg, const ushort_t* __restrict__ w1bT,
    const float* __restrict__ b1, ushort_t* __restrict__ hbuf, const int* __restrict__ ctl) {
  int e = blockIdx.z;
  int cp = ctl[48 + e];
  if ((int)blockIdx.x * 128 >= cp) return;
  int rowbase = ctl[32 + e] + blockIdx.x * 128;
  const ushort_t* Ab = xg + (size_t)rowbase * D_DIM;
  const ushort_t* Bb = w1bT + ((size_t)e * H_DIM + (size_t)blockIdx.y * 128) * D_DIM;

  __shared__ __align__(16) short As[128 * 32];
  __shared__ __align__(16) short Bs[128 * 32];

  int tid = threadIdx.x;
  int wave = tid >> 6, lane = tid & 63;
  int wm = wave >> 1, wn = wave & 1;
  int m16 = lane & 15, quad = lane >> 4;

  f32x4 acc[4][4];
#pragma unroll
  for (int i = 0; i < 4; i++)
#pragma unroll
    for (int j = 0; j < 4; j++) acc[i][j] = (f32x4){0.f, 0.f, 0.f, 0.f};

  int srow = wave * 16 + (lane >> 2);       // staging row (this lane), +64 for 2nd call
  int scol = (lane & 3) * 8;                // staging col (8 bf16 = 16B)

  for (int k0 = 0; k0 < D_DIM; k0 += 32) {
    g2l16(Ab + (size_t)srow * D_DIM + k0 + scol, As + (wave * 16) * 32);
    g2l16(Ab + (size_t)(srow + 64) * D_DIM + k0 + scol, As + (64 + wave * 16) * 32);
    g2l16(Bb + (size_t)srow * D_DIM + k0 + scol, Bs + (wave * 16) * 32);
    g2l16(Bb + (size_t)(srow + 64) * D_DIM + k0 + scol, Bs + (64 + wave * 16) * 32);
    __syncthreads();
    s16x8 a[4], b[4];
#pragma unroll
    for (int i = 0; i < 4; i++)
      a[i] = *(const s16x8*)(As + ((wm * 64 + i * 16 + m16) * 32 + quad * 8));
#pragma unroll
    for (int j = 0; j < 4; j++)
      b[j] = *(const s16x8*)(Bs + ((wn * 64 + j * 16 + m16) * 32 + quad * 8));
#pragma unroll
    for (int i = 0; i < 4; i++)
#pragma unroll
      for (int j = 0; j < 4; j++)
        acc[i][j] = __builtin_amdgcn_mfma_f32_16x16x32_bf16(a[i], b[j], acc[i][j], 0, 0, 0);
    __syncthreads();
  }

  int nbase = blockIdx.y * 128 + wn * 64;
  const float* b1e = b1 + (size_t)e * H_DIM;
#pragma unroll
  for (int j = 0; j < 4; j++) {
    int n = nbase + j * 16 + m16;
    float bb = b1e[n];
#pragma unroll
    for (int i = 0; i < 4; i++) {
      int rl = wm * 64 + i * 16 + quad * 4;
#pragma unroll
      for (int r = 0; r < 4; r++) {
        float v = acc[i][j][r] + bb;
        float sv = v / (1.f + __expf(-v));   // silu
        hbuf[(size_t)(rowbase + rl + r) * H_DIM + n] = f2bf(sv);
      }
    }
  }
}

// ---------- GEMM2: out[token] += gate * (h @ w2-tile) ----------
__global__ __launch_bounds__(256) void gemm2_kernel(
    const ushort_t* __restrict__ hbuf, const ushort_t* __restrict__ w2bT,
    const int* __restrict__ row_token, const float* __restrict__ row_gate,
    float* __restrict__ out, const int* __restrict__ ctl) {
  int e = blockIdx.z;
  int cp = ctl[48 + e];
  if ((int)blockIdx.x * 128 >= cp) return;
  int rowbase = ctl[32 + e] + blockIdx.x * 128;
  const ushort_t* Ab = hbuf + (size_t)rowbase * H_DIM;
  const ushort_t* Bb = w2bT + ((size_t)e * D_DIM + (size_t)blockIdx.y * 128) * H_DIM;

  __shared__ __align__(16) short As[128 * 32];
  __shared__ __align__(16) short Bs[128 * 32];

  int tid = threadIdx.x;
  int wave = tid >> 6, lane = tid & 63;
  int wm = wave >> 1, wn = wave & 1;
  int m16 = lane & 15, quad = lane >> 4;

  f32x4 acc[4][4];
#pragma unroll
  for (int i = 0; i < 4; i++)
#pragma unroll
    for (int j = 0; j < 4; j++) acc[i][j] = (f32x4){0.f, 0.f, 0.f, 0.f};

  int srow = wave * 16 + (lane >> 2);
  int scol = (lane & 3) * 8;

  for (int k0 = 0; k0 < H_DIM; k0 += 32) {
    g2l16(Ab + (size_t)srow * H_DIM + k0 + scol, As + (wave * 16) * 32);
    g2l16(Ab + (size_t)(srow + 64) * H_DIM + k0 + scol, As + (64 + wave * 16) * 32);
    g2l16(Bb + (size_t)srow * H_DIM + k0 + scol, Bs + (wave * 16) * 32);
    g2l16(Bb + (size_t)(srow + 64) * H_DIM + k0 + scol, Bs + (64 + wave * 16) * 32);
    __syncthreads();
    s16x8 a[4], b[4];
#pragma unroll
    for (int i = 0; i < 4; i++)
      a[i] = *(const s16x8*)(As + ((wm * 64 + i * 16 + m16) * 32 + quad * 8));
#pragma unroll
    for (int j = 0; j < 4; j++)
      b[j] = *(const s16x8*)(Bs + ((wn * 64 + j * 16 + m16) * 32 + quad * 8));
#pragma unroll
    for (int i = 0; i < 4; i++)
#pragma unroll
      for (int j = 0; j < 4; j++)
        acc[i][j] = __builtin_amdgcn_mfma_f32_16x16x32_bf16(a[i], b[j], acc[i][j], 0, 0, 0);
    __syncthreads();
  }

  int nbase = blockIdx.y * 128 + wn * 64;
#pragma unroll
  for (int i = 0; i < 4; i++) {
    int rl = wm * 64 + i * 16 + quad * 4;
#pragma unroll
    for (int r = 0; r < 4; r++) {
      int row = rowbase + rl + r;
      float g = row_gate[row];                 // 0 for pad rows
      int t = row_token[row];
#pragma unroll
      for (int j = 0; j < 4; j++) {
        int n = nbase + j * 16 + m16;
        atomicAdd(&out[(size_t)t * D_DIM + n], g * acc[i][j][r]);
      }
    }
  }
}

extern "C" void kernel_launch(void* const* d_in, const int* in_sizes, int n_in,
                              void* d_out, int out_size, void* d_ws, size_t ws_size,
                              hipStream_t stream) {
  const float* x      = (const float*)d_in[0];
  const float* w_gate = (const float*)d_in[1];
  const float* b_gate = (const float*)d_in[2];
  const float* w1     = (const float*)d_in[3];
  const float* b1     = (const float*)d_in[4];
  const float* w2     = (const float*)d_in[5];
  const float* b2     = (const float*)d_in[6];
  float* out = (float*)d_out;
  char* ws = (char*)d_ws;

  int*      ctl       = (int*)(ws + OFF_CTL);
  int*      row_token = (int*)(ws + OFF_ROWTOK);
  float*    row_gate  = (float*)(ws + OFF_ROWGATE);
  int*      tok_e     = (int*)(ws + OFF_TOKE);
  float*    tok_g     = (float*)(ws + OFF_TOKG);
  ushort_t* xg        = (ushort_t*)(ws + OFF_XG);
  ushort_t* hbuf      = (ushort_t*)(ws + OFF_HBUF);
  ushort_t* w1bT      = (ushort_t*)(ws + OFF_W1BT);
  ushort_t* w2bT      = (ushort_t*)(ws + OFF_W2BT);

  // zero control + routing arrays (ws is poisoned 0xAA before every call)
  hipMemsetAsync(ws, 0, 81920, stream);

  gate_kernel<<<S_LEN / 4, 256, 0, stream>>>(x, w_gate, b_gate, tok_e, tok_g, ctl);
  scan_kernel<<<1, 64, 0, stream>>>(ctl);
  assign_kernel<<<32, 256, 0, stream>>>(tok_e, tok_g, ctl, row_token, row_gate);
  gather_kernel<<<ROWS_CAP, 256, 0, stream>>>(x, row_token, xg);
  convT_kernel<<<dim3(H_DIM / 32, D_DIM / 32, E_NUM), dim3(32, 8), 0, stream>>>(w1, w1bT, D_DIM, H_DIM);
  convT_kernel<<<dim3(D_DIM / 32, H_DIM / 32, E_NUM), dim3(32, 8), 0, stream>>>(w2, w2bT, H_DIM, D_DIM);
  init_out_kernel<<<S_LEN, 256, 0, stream>>>(b2, tok_e, tok_g, out);
  gemm1_kernel<<<dim3(32, H_DIM / 128, E_NUM), 256, 0, stream>>>(xg, w1bT, b1, hbuf, ctl);
  gemm2_kernel<<<dim3(32, D_DIM / 128, E_NUM), 256, 0, stream>>>(hbuf, w2bT, row_token, row_gate, out, ctl);
}